// Round 3
// baseline (234.108 us; speedup 1.0000x reference)
//
#include <hip/hip_runtime.h>
#include <stdint.h>

// B=16, CIN=512, COUT=128, H=W=64
#define NB    16
#define CIN   512
#define COUT  128
#define HW    4096
#define BN    128             // N-tile per block (512B row-chunks)
#define BK    32              // K-tile per iteration
#define NIT   (CIN / BK)      // 16
// grid = 16 b x 32 n-tiles = 512 blocks x 512 thr = 2 blocks/CU

using bf16x8  = __attribute__((ext_vector_type(8))) __bf16;
using floatx4 = __attribute__((ext_vector_type(4))) float;

// RNE float -> bf16 bits (proven in previous session; identical numerics to modw)
__device__ __forceinline__ unsigned short f2bf_bits(float f) {
    union { float f; unsigned u; } v; v.f = f;
    return (unsigned short)((v.u + 0x7fffu + ((v.u >> 16) & 1u)) >> 16);
}

// async global->LDS, 16B/lane; LDS dest = wave-uniform base + lane*16.
#define GLD16(g, l)                                                            \
    __builtin_amdgcn_global_load_lds(                                          \
        (const __attribute__((address_space(1))) void*)(g),                    \
        (__attribute__((address_space(3))) void*)(l), 16, 0, 0)

// ---------------------------------------------------------------------------
// FUSED kernel: A-fragments (weight*style -> bf16) computed in-register from
// L2-resident weight (256 KB, shared by all blocks) + L1-hot style (2 KB/b).
// Eliminates: modw kernel + launch gap, mw HBM round-trip, A-DMA, A ds_reads.
// B path unchanged: triple-buffered LDS, raw s_barrier + counted vmcnt(2)
// (2 B-DMA instrs/wave/iter; reg-loads issued BEFORE the DMAs so compiler
// waits retire only the weight loads, keeping the B prefetch in flight).
// ---------------------------------------------------------------------------
__global__ __launch_bounds__(512, 4)
void modconv_fused_kernel(const float* __restrict__ x,
                          const float* __restrict__ style,
                          const float* __restrict__ weight,
                          float* __restrict__ out)
{
    __shared__ __align__(16) float Blds[3][BK * BN];   // [k][n]  3 x 16 KB

    const int tid  = threadIdx.x;
    const int lane = tid & 63;
    const int wave = tid >> 6;          // 0..7
    const int quad = lane >> 4;
    const int l15  = lane & 15;

    const int b  = blockIdx.x >> 5;
    const int n0 = (blockIdx.x & 31) * BN;

    const char*  xbb  = (const char*)(x + (size_t)b * CIN * HW + n0);
    float*       outb = out + (size_t)b * COUT * HW + n0;

    const int wm = (wave & 1) * 64;     // wave tile 64(m) x 32(n)
    const int wn = (wave >> 1) * 32;

    // per-thread A sources: weight rows m = wm + tm*16 + l15, k-window
    // it*32 + quad*8 .. +7 ; style[b][same k-window]
    const float* wr0 = weight + (size_t)(wm + 0 * 16 + l15) * CIN + quad * 8;
    const float* wr1 = weight + (size_t)(wm + 1 * 16 + l15) * CIN + quad * 8;
    const float* wr2 = weight + (size_t)(wm + 2 * 16 + l15) * CIN + quad * 8;
    const float* wr3 = weight + (size_t)(wm + 3 * 16 + l15) * CIN + quad * 8;
    const float* sb  = style + (size_t)b * CIN + quad * 8;

    // B GLD geometry: instr g covers rows 2g,2g+1 (512B each).
    const int brsel = lane >> 5;        // 0/1: which of the two rows
    const int bcol  = lane & 31;        // float4 column within row

    floatx4 acc[4][2];
    #pragma unroll
    for (int i = 0; i < 4; ++i)
        #pragma unroll
        for (int j = 0; j < 2; ++j)
            acc[i][j] = (floatx4){0.f, 0.f, 0.f, 0.f};

    // per-wave: exactly 2 B-GLD = 2 vmcnt events per stage
#define BSTAGE(K0, BUF)                                                        \
    {                                                                          \
        char* bl = (char*)&Blds[BUF][0];                                       \
        _Pragma("unroll")                                                      \
        for (int g = 0; g < 2; ++g) {                                          \
            const int gi = wave * 2 + g;              /* 0..15 */              \
            const int r  = gi * 2 + brsel;            /* row 0..31 */          \
            GLD16(xbb + (size_t)((K0) + r) * (HW * 4) + bcol * 16,             \
                  bl + gi * 1024);                                             \
        }                                                                      \
    }

    // A-fragment build: 8 weight dwordx4 + 2 style dwordx4 -> 4x bf16x8
#define ABUILD(K0, AF)                                                         \
    {                                                                          \
        const float4 sv0 = *(const float4*)(sb + (K0));                        \
        const float4 sv1 = *(const float4*)(sb + (K0) + 4);                    \
        const float4 w00 = *(const float4*)(wr0 + (K0));                       \
        const float4 w01 = *(const float4*)(wr0 + (K0) + 4);                   \
        const float4 w10 = *(const float4*)(wr1 + (K0));                       \
        const float4 w11 = *(const float4*)(wr1 + (K0) + 4);                   \
        const float4 w20 = *(const float4*)(wr2 + (K0));                       \
        const float4 w21 = *(const float4*)(wr2 + (K0) + 4);                   \
        const float4 w30 = *(const float4*)(wr3 + (K0));                       \
        const float4 w31 = *(const float4*)(wr3 + (K0) + 4);                   \
        union { unsigned short us[8]; bf16x8 v; } p0, p1, p2, p3;              \
        p0.us[0] = f2bf_bits(w00.x * sv0.x); p0.us[1] = f2bf_bits(w00.y * sv0.y); \
        p0.us[2] = f2bf_bits(w00.z * sv0.z); p0.us[3] = f2bf_bits(w00.w * sv0.w); \
        p0.us[4] = f2bf_bits(w01.x * sv1.x); p0.us[5] = f2bf_bits(w01.y * sv1.y); \
        p0.us[6] = f2bf_bits(w01.z * sv1.z); p0.us[7] = f2bf_bits(w01.w * sv1.w); \
        p1.us[0] = f2bf_bits(w10.x * sv0.x); p1.us[1] = f2bf_bits(w10.y * sv0.y); \
        p1.us[2] = f2bf_bits(w10.z * sv0.z); p1.us[3] = f2bf_bits(w10.w * sv0.w); \
        p1.us[4] = f2bf_bits(w11.x * sv1.x); p1.us[5] = f2bf_bits(w11.y * sv1.y); \
        p1.us[6] = f2bf_bits(w11.z * sv1.z); p1.us[7] = f2bf_bits(w11.w * sv1.w); \
        p2.us[0] = f2bf_bits(w20.x * sv0.x); p2.us[1] = f2bf_bits(w20.y * sv0.y); \
        p2.us[2] = f2bf_bits(w20.z * sv0.z); p2.us[3] = f2bf_bits(w20.w * sv0.w); \
        p2.us[4] = f2bf_bits(w21.x * sv1.x); p2.us[5] = f2bf_bits(w21.y * sv1.y); \
        p2.us[6] = f2bf_bits(w21.z * sv1.z); p2.us[7] = f2bf_bits(w21.w * sv1.w); \
        p3.us[0] = f2bf_bits(w30.x * sv0.x); p3.us[1] = f2bf_bits(w30.y * sv0.y); \
        p3.us[2] = f2bf_bits(w30.z * sv0.z); p3.us[3] = f2bf_bits(w30.w * sv0.w); \
        p3.us[4] = f2bf_bits(w31.x * sv1.x); p3.us[5] = f2bf_bits(w31.y * sv1.y); \
        p3.us[6] = f2bf_bits(w31.z * sv1.z); p3.us[7] = f2bf_bits(w31.w * sv1.w); \
        AF[0] = p0.v; AF[1] = p1.v; AF[2] = p2.v; AF[3] = p3.v;                \
    }

#define COMPUTE(BUF, AF)                                                       \
    {                                                                          \
        bf16x8 bfr[2];                                                         \
        _Pragma("unroll")                                                      \
        for (int tn = 0; tn < 2; ++tn) {                                       \
            union { unsigned short us[8]; bf16x8 v; } pk;                      \
            _Pragma("unroll")                                                  \
            for (int j = 0; j < 8; ++j)                                        \
                pk.us[j] = f2bf_bits(Blds[BUF][(quad * 8 + j) * BN + wn + tn * 16 + l15]); \
            bfr[tn] = pk.v;                                                    \
        }                                                                      \
        _Pragma("unroll")                                                      \
        for (int tm = 0; tm < 4; ++tm)                                         \
            _Pragma("unroll")                                                  \
            for (int tn = 0; tn < 2; ++tn)                                     \
                acc[tm][tn] = __builtin_amdgcn_mfma_f32_16x16x32_bf16(         \
                    AF[tm], bfr[tn], acc[tm][tn], 0, 0, 0);                    \
    }

    // prologue: tiles 0,1 -> slots 0,1 (4 B-DMA in flight)
    BSTAGE(0, 0)
    BSTAGE(BK, 1)

    // invariant at top of iter it: outstanding = B(it) [oldest 2] + B(it+1) [2].
    // vmcnt(2) retires B(it); B(it+1) stays in flight across the barrier.
    // Body: reg-loads (weight/style) issued BEFORE B(it+2) DMA, so the
    // compiler's register-dependence wait is vmcnt(2), not vmcnt(0).
    int sc = 0;          // compute slot = it % 3
    int ss = 2;          // stage slot   = (it+2) % 3
    #pragma unroll 1
    for (int it = 0; it < NIT - 1; ++it) {
        asm volatile("s_waitcnt vmcnt(2)" ::: "memory");
        __builtin_amdgcn_s_barrier();
        bf16x8 af[4];
        ABUILD(it * BK, af)
        if (it + 2 < NIT) BSTAGE((it + 2) * BK, ss)
        COMPUTE(sc, af)
        sc = (sc == 2) ? 0 : sc + 1;
        ss = (ss == 2) ? 0 : ss + 1;
    }
    // it = 15: only B(15) outstanding -> full drain
    asm volatile("s_waitcnt vmcnt(0)" ::: "memory");
    __builtin_amdgcn_s_barrier();
    {
        bf16x8 af[4];
        ABUILD((NIT - 1) * BK, af)
        COMPUTE(sc, af)
    }
#undef BSTAGE
#undef ABUILD
#undef COMPUTE

    // epilogue: C/D layout col(n)=l15, row(o)=quad*4+reg
    #pragma unroll
    for (int tm = 0; tm < 4; ++tm) {
        const int o = wm + tm * 16 + quad * 4;
        #pragma unroll
        for (int tn = 0; tn < 2; ++tn) {
            const int n = wn + tn * 16 + l15;
            #pragma unroll
            for (int r = 0; r < 4; ++r)
                outb[(size_t)(o + r) * HW + n] = acc[tm][tn][r];
        }
    }
}

extern "C" void kernel_launch(void* const* d_in, const int* in_sizes, int n_in,
                              void* d_out, int out_size, void* d_ws, size_t ws_size,
                              hipStream_t stream) {
    const float* x      = (const float*)d_in[0];   // (16, 512, 64, 64) fp32
    const float* style  = (const float*)d_in[1];   // (16, 512) fp32
    const float* weight = (const float*)d_in[2];   // (128, 512) fp32
    float* out = (float*)d_out;                    // (16, 128, 64, 64) fp32
    (void)d_ws; (void)ws_size;

    modconv_fused_kernel<<<dim3(NB * 32), dim3(512), 0, stream>>>(x, style, weight, out);
}

// Round 4
// 205.784 us; speedup vs baseline: 1.1376x; 1.1376x over previous
//
#include <hip/hip_runtime.h>
#include <stdint.h>

// B=16, CIN=512, COUT=128, H=W=64
#define NB    16
#define CIN   512
#define COUT  128
#define HW    4096
#define BN    128             // N-tile per block
#define BK    32              // K-tile per iteration
#define NIT   (CIN / BK)      // 16
// grid = 16 b x 32 n-tiles = 512 blocks x 512 thr = 2 blocks/CU

using bf16x8  = __attribute__((ext_vector_type(8))) __bf16;
using floatx4 = __attribute__((ext_vector_type(4))) float;

// RNE float -> bf16 bits (proven in previous session)
__device__ __forceinline__ unsigned short f2bf_bits(float f) {
    union { float f; unsigned u; } v; v.f = f;
    return (unsigned short)((v.u + 0x7fffu + ((v.u >> 16) & 1u)) >> 16);
}

// async global->LDS, 16B/lane; LDS dest = wave-uniform base + lane*16.
#define GLD16(g, l)                                                            \
    __builtin_amdgcn_global_load_lds(                                          \
        (const __attribute__((address_space(1))) void*)(g),                    \
        (__attribute__((address_space(3))) void*)(l), 16, 0, 0)

// ---------------------------------------------------------------------------
// Precompute mw[b][k8][m][j] = bf16(weight[m][k8*8+j] * style[b][k8*8+j])
// = the 16x16x32 A-fragment layout, contiguous 8KB slab per K-tile.
// ---------------------------------------------------------------------------
__global__ __launch_bounds__(256)
void modw_kernel(const float* __restrict__ style,
                 const float* __restrict__ weight,
                 __bf16* __restrict__ mw)
{
    const int id = blockIdx.x * 256 + threadIdx.x;   // 512 blocks
    const int k8 = id & 63;
    const int m  = (id >> 6) & 127;
    const int b  = id >> 13;

    const float4 w0 = *(const float4*)(weight + m * CIN + k8 * 8);
    const float4 w1 = *(const float4*)(weight + m * CIN + k8 * 8 + 4);
    const float4 s0 = *(const float4*)(style + b * CIN + k8 * 8);
    const float4 s1 = *(const float4*)(style + b * CIN + k8 * 8 + 4);

    union { unsigned short us[8]; bf16x8 v; } pk;
    pk.us[0] = f2bf_bits(w0.x * s0.x);
    pk.us[1] = f2bf_bits(w0.y * s0.y);
    pk.us[2] = f2bf_bits(w0.z * s0.z);
    pk.us[3] = f2bf_bits(w0.w * s0.w);
    pk.us[4] = f2bf_bits(w1.x * s1.x);
    pk.us[5] = f2bf_bits(w1.y * s1.y);
    pk.us[6] = f2bf_bits(w1.z * s1.z);
    pk.us[7] = f2bf_bits(w1.w * s1.w);
    *(bf16x8*)(mw + ((size_t)(b * 64 + k8) * 128 + m) * 8) = pk.v;
}

// ---------------------------------------------------------------------------
// 128x128 block tile, 512 threads (8 waves of 64x32), double-buffered.
// B is reg-staged: global->reg (8x 256B coalesced wave-loads), fp32->bf16
// converted ONCE per element, ds_write_b128 in MFMA fragment layout
// Bf[kg][n][8]. B-fragment read = 1 conflict-free ds_read_b128 (was 16x
// ds_read_b32 with 4-way conflicts). A stays on the global_load_lds DMA.
// Raw s_barrier + counted vmcnt: A-DMA and next-next B-loads stay in
// flight across the barrier.
// ---------------------------------------------------------------------------
__global__ __launch_bounds__(512, 4)
void modconv1x1_kernel(const float* __restrict__ x,
                       const __bf16* __restrict__ mw,
                       float* __restrict__ out)
{
    __shared__ __align__(16) __bf16 Alds[2][4096];        // [k8][m][j] 2 x 8 KB
    __shared__ __align__(16) __bf16 Bfs[2][4 * 128 * 8];  // [kg][n][j] 2 x 8 KB

    const int tid  = threadIdx.x;
    const int lane = tid & 63;
    const int wave = tid >> 6;          // 0..7
    const int quad = lane >> 4;
    const int l15  = lane & 15;

    const int b  = blockIdx.x >> 5;
    const int n0 = (blockIdx.x & 31) * BN;

    float*       outb = out + (size_t)b * COUT * HW + n0;
    const char*  mwb  = (const char*)mw + (size_t)b * (64 * 128 * 16);  // 128KB/batch

    const int wm = (wave & 1) * 64;     // wave tile 64(m) x 32(n)
    const int wn = (wave >> 1) * 32;

    // B staging geometry: thread covers kg = tid>>7 (k-slab of 8), bn = tid&127
    const int kg = tid >> 7;            // 0..3
    const int bn = tid & 127;           // n within tile
    const float* xbn = x + (size_t)b * CIN * HW + (size_t)kg * 8 * HW + n0 + bn;

    floatx4 acc[4][2];
    #pragma unroll
    for (int i = 0; i < 4; ++i)
        #pragma unroll
        for (int j = 0; j < 2; ++j)
            acc[i][j] = (floatx4){0.f, 0.f, 0.f, 0.f};

    // issue 8 global dword loads for B(T) into reg set XR (each wave-instr:
    // 64 consecutive n = 256B contiguous)
#define SISSUE(T, XR)                                                          \
    {                                                                          \
        const float* xp = xbn + (size_t)(T) * BK * HW;                         \
        _Pragma("unroll")                                                      \
        for (int j = 0; j < 8; ++j) XR[j] = xp[(size_t)j * HW];                \
    }

    // convert + pack + fragment-layout LDS write (1KB contiguous per wave)
#define SWRITE(T, XR)                                                          \
    {                                                                          \
        union { unsigned short us[8]; bf16x8 v; } pk;                          \
        _Pragma("unroll")                                                      \
        for (int j = 0; j < 8; ++j) pk.us[j] = f2bf_bits(XR[j]);               \
        *(bf16x8*)&Bfs[(T) & 1][(kg * 128 + bn) * 8] = pk.v;                   \
    }

    // A-DMA: 1 instr/wave, 8KB tile -> Alds[(T)&1]
#define ADMA(T)                                                                \
    {                                                                          \
        const char* at = mwb + (size_t)(T) * 8192;                             \
        GLD16(at + wave * 1024 + lane * 16,                                    \
              (char*)&Alds[(T) & 1][0] + wave * 1024);                        \
    }

#define COMPUTE(BUF)                                                           \
    {                                                                          \
        bf16x8 af[4];                                                          \
        _Pragma("unroll")                                                      \
        for (int tm = 0; tm < 4; ++tm)                                         \
            af[tm] = *(const bf16x8*)&Alds[BUF][(quad * 128 + wm + tm * 16 + l15) * 8]; \
        bf16x8 bfr[2];                                                         \
        _Pragma("unroll")                                                      \
        for (int tn = 0; tn < 2; ++tn)                                         \
            bfr[tn] = *(const bf16x8*)&Bfs[BUF][(quad * 128 + wn + tn * 16 + l15) * 8]; \
        _Pragma("unroll")                                                      \
        for (int tm = 0; tm < 4; ++tm)                                         \
            _Pragma("unroll")                                                  \
            for (int tn = 0; tn < 2; ++tn)                                     \
                acc[tm][tn] = __builtin_amdgcn_mfma_f32_16x16x32_bf16(         \
                    af[tm], bfr[tn], acc[tm][tn], 0, 0, 0);                    \
    }

    // full-pipeline body, valid for IT <= 13:
    // queue on entry: [B(IT+1) x8]. ADMA adds A(IT+1); SISSUE adds B(IT+2)x8.
    // SWRITE's compiler wait retires B(IT+1) (oldest). Our vmcnt(8) retires
    // A(IT+1), leaving B(IT+2)x8 in flight across the barrier.
#define BODYF(IT, XC, XN)                                                      \
    {                                                                          \
        ADMA((IT) + 1)                                                         \
        COMPUTE((IT) & 1)                                                      \
        SISSUE((IT) + 2, XN)                                                   \
        SWRITE((IT) + 1, XC)                                                   \
        asm volatile("s_waitcnt vmcnt(8) lgkmcnt(0)" ::: "memory");            \
        __builtin_amdgcn_s_barrier();                                          \
    }

    float xa[8], xb[8];

    // prologue: B(0) -> Bfs[0], A(0) -> Alds[0], issue B(1)
    SISSUE(0, xa)
    ADMA(0)
    SWRITE(0, xa)        // compiler waits B(0) regs; A(0) may stay in flight
    SISSUE(1, xb)
    asm volatile("s_waitcnt vmcnt(8) lgkmcnt(0)" ::: "memory");  // retire A(0)
    __builtin_amdgcn_s_barrier();

    // main loop: IT = 0..13 (even body consumes xb, issues xa; odd vice versa)
    #pragma unroll 1
    for (int it2 = 0; it2 < 7; ++it2) {
        const int it = it2 * 2;
        BODYF(it,     xb, xa)
        BODYF(it + 1, xa, xb)
    }
    // IT = 14: no SISSUE(16); drain A(15) fully before last barrier
    {
        ADMA(15)
        COMPUTE(0)
        SWRITE(15, xb)
        asm volatile("s_waitcnt vmcnt(0) lgkmcnt(0)" ::: "memory");
        __builtin_amdgcn_s_barrier();
    }
    // IT = 15: compute only
    COMPUTE(1)

#undef BODYF
#undef COMPUTE
#undef ADMA
#undef SWRITE
#undef SISSUE

    // epilogue: C/D layout col(n)=l15, row(o)=quad*4+reg
    #pragma unroll
    for (int tm = 0; tm < 4; ++tm) {
        const int o = wm + tm * 16 + quad * 4;
        #pragma unroll
        for (int tn = 0; tn < 2; ++tn) {
            const int n = wn + tn * 16 + l15;
            #pragma unroll
            for (int r = 0; r < 4; ++r)
                outb[(size_t)(o + r) * HW + n] = acc[tm][tn][r];
        }
    }
}

extern "C" void kernel_launch(void* const* d_in, const int* in_sizes, int n_in,
                              void* d_out, int out_size, void* d_ws, size_t ws_size,
                              hipStream_t stream) {
    const float* x      = (const float*)d_in[0];   // (16, 512, 64, 64) fp32
    const float* style  = (const float*)d_in[1];   // (16, 512) fp32
    const float* weight = (const float*)d_in[2];   // (128, 512) fp32
    float* out = (float*)d_out;                    // (16, 128, 64, 64) fp32
    __bf16* mw = (__bf16*)d_ws;                    // 2 MB modulated weights

    modw_kernel<<<dim3(512), dim3(256), 0, stream>>>(style, weight, mw);
    modconv1x1_kernel<<<dim3(NB * 32), dim3(512), 0, stream>>>(x, mw, out);
}